// Round 1
// baseline (341.013 us; speedup 1.0000x reference)
//
#include <hip/hip_runtime.h>
#include <hip/hip_bf16.h>
#include <math.h>

// CrossAttention fused pipeline, bf16 MFMA everywhere.
// B=64, N=256, C=1024, H=16, hd=64, sem=768, M=B*N=16384.
// ws layout (~200.4 MB): flag, cos/sin tables, biasF, q_bf16(33.5M, reused as
// attn_out), kv_bf16(25.2M), WqT(2.1M), WkvT(3.1M), WprojT(2.1M),
// qh(33.5M), k(33.5M), v(33.5M), vT(33.5M).

typedef unsigned int uint;
typedef __attribute__((ext_vector_type(8))) short s16x8;
typedef __attribute__((ext_vector_type(16))) short s16x16;
typedef __attribute__((ext_vector_type(4))) float f32x4;

#define AS1 __attribute__((address_space(1)))
#define AS3 __attribute__((address_space(3)))

__device__ __forceinline__ short f2bf(float x){
  union{float f;uint u;}v; v.f=x;
  return (short)((v.u + 0x7FFFu + ((v.u>>16)&1u))>>16);   // RNE
}
__device__ __forceinline__ float bf2f(short s){
  union{float f;uint u;}v; v.u=((uint)(unsigned short)s)<<16; return v.f;
}
__device__ __forceinline__ uint packbf(float a,float b){
  return (uint)(unsigned short)f2bf(a) | ((uint)(unsigned short)f2bf(b)<<16);
}
__device__ __forceinline__ void gl_lds16(const void* g, void* l){
  __builtin_amdgcn_global_load_lds((const AS1 uint*)g, (AS3 uint*)l, 16, 0, 0);
}
__device__ __forceinline__ s16x8 ld16(const short* p){ return *(const s16x8*)p; }

// ---------------- dtype detection -------------------------------------------
// bits[14:7] of each 32-bit word: bf16-packed N(0,1) -> exponent of low elem,
// ~99% in [120,130]; fp32 -> mantissa bits, ~4%.  flag: 0 = bf16, 1 = fp32.
__global__ void k_detect(const uint* q, int* flag){
  __shared__ int cnt;
  if(threadIdx.x==0) cnt=0;
  __syncthreads();
  int c=0;
  for(int i=threadIdx.x;i<4096;i+=256){
    uint e=(q[i]>>7)&0xFFu;
    if(e>=120u && e<=130u) c++;
  }
  atomicAdd(&cnt,c);
  __syncthreads();
  if(threadIdx.x==0) *flag = (cnt>2048)?0:1;
}

// ---------------- conversions -----------------------------------------------
__global__ void k_convert(const void* src, short* dst, long n8, const int* flag){
  int f=*flag;
  long stride=(long)gridDim.x*blockDim.x;
  for(long i=(long)blockIdx.x*blockDim.x+threadIdx.x;i<n8;i+=stride){
    s16x8 o;
    if(f){
      const float4* s=(const float4*)src;
      float4 a=s[i*2], b=s[i*2+1];
      o[0]=f2bf(a.x);o[1]=f2bf(a.y);o[2]=f2bf(a.z);o[3]=f2bf(a.w);
      o[4]=f2bf(b.x);o[5]=f2bf(b.y);o[6]=f2bf(b.z);o[7]=f2bf(b.w);
    }else{
      o=((const s16x8*)src)[i];
    }
    ((s16x8*)dst)[i]=o;
  }
}

// W (K x Nn) row-major -> WT (Nn x K) row-major (bf16).
__global__ void k_transpose(const void* W, short* WT, int K, int Nn, const int* flag){
  int f=*flag;
  long total=(long)Nn*(K/8);
  long stride=(long)gridDim.x*blockDim.x;
  for(long idx=(long)blockIdx.x*blockDim.x+threadIdx.x;idx<total;idx+=stride){
    int n=(int)(idx%Nn); int kc=(int)(idx/Nn); int k0=kc*8;
    s16x8 o;
    #pragma unroll
    for(int j=0;j<8;j++){
      o[j]= f ? f2bf(((const float*)W)[(long)(k0+j)*Nn+n])
              : ((const short*)W)[(long)(k0+j)*Nn+n];
    }
    *(s16x8*)&WT[(long)n*K+k0]=o;
  }
}

// RoPE tables, double precision to match numpy float64->float32.
__global__ void k_tables(float* cosT, float* sinT){
  int t=blockIdx.x*blockDim.x+threadIdx.x;
  if(t>=256*64) return;
  int n=t>>6, d=t&63;
  int i=n>>4, j=n&15;
  int p=(d&31)>>1;
  double fr=pow(10000.0, -(double)(2*p)/32.0);
  double tt=(d<32)?(double)i:(double)j;
  double a=tt*fr;
  cosT[t]=(float)cos(a);
  sinT[t]=(float)sin(a);
}

__global__ void k_bias(const void* b, float* bo, const int* flag){
  int t=blockIdx.x*blockDim.x+threadIdx.x;
  if(t<1024) bo[t] = (*flag)? ((const float*)b)[t] : bf2f(((const short*)b)[t]);
}

// ---------------- GEMM: C[M,N] = A[M,K] * BT[N,K]^T, fused epilogues --------
// EPI 0: RoPE+scale -> qh (B,H,N,64) bf16
// EPI 1: n<1024: RoPE -> k (B,H,N,64); else: -> v (B,H,N,64)
// EPI 2: +bias -> d_out (fp32 or bf16 per flag)
template<int EPI>
__launch_bounds__(256,2)
__global__ void k_gemm(const short* A, const short* BT, int Kdim,
                       short* out0, short* out1,
                       const float* cosT, const float* sinT,
                       const float* bias, const int* flag, void* dout){
  __shared__ __align__(16) short Alds[128*32];
  __shared__ __align__(16) short Blds[128*32];
  const int tid=threadIdx.x, lane=tid&63;
  const int wave=tid>>6, wm=wave>>1, wn=wave&1;
  const int tn=blockIdx.x, tm=blockIdx.y;
  const int fl=*flag;
  f32x4 acc[4][4]={};
  const short* Ag=A+(long)tm*128*Kdim;
  const short* Bg=BT+(long)tn*128*Kdim;
  const int r0=tid, r1=256+tid;
  const int row0=r0>>2, c0=r0&3, row1=r1>>2, c1=r1&3;
  const int sw0=(c0^(row0&3))*8, sw1=(c1^(row1&3))*8;

  for(int k0=0;k0<Kdim;k0+=32){
    __syncthreads();
    gl_lds16(Ag+(long)row0*Kdim+k0+sw0, &Alds[r0*8]);
    gl_lds16(Ag+(long)row1*Kdim+k0+sw1, &Alds[r1*8]);
    gl_lds16(Bg+(long)row0*Kdim+k0+sw0, &Blds[r0*8]);
    gl_lds16(Bg+(long)row1*Kdim+k0+sw1, &Blds[r1*8]);
    asm volatile("s_waitcnt vmcnt(0)" ::: "memory");
    __syncthreads();
    s16x8 af[4], bfr[4];
    #pragma unroll
    for(int rb=0;rb<4;rb++){
      int ar=wm*64+rb*16+(lane&15);
      af[rb]=*(const s16x8*)&Alds[ar*32+(((lane>>4)^(ar&3))*8)];
    }
    #pragma unroll
    for(int cb=0;cb<4;cb++){
      int br=wn*64+cb*16+(lane&15);
      bfr[cb]=*(const s16x8*)&Blds[br*32+(((lane>>4)^(br&3))*8)];
    }
    #pragma unroll
    for(int rb=0;rb<4;rb++)
      #pragma unroll
      for(int cb=0;cb<4;cb++)
        acc[rb][cb]=__builtin_amdgcn_mfma_f32_16x16x32_bf16(af[rb],bfr[cb],acc[rb][cb],0,0,0);
  }

  const int mbase=tm*128+wm*64, nbase=tn*128+wn*64;
  #pragma unroll
  for(int rb=0;rb<4;rb++)
  #pragma unroll
  for(int cb=0;cb<4;cb++)
  #pragma unroll
  for(int r=0;r<4;r++){
    int m=mbase+rb*16+(lane>>4)*4+r;
    int n=nbase+cb*16+(lane&15);
    float v=acc[rb][cb][r];
    if(EPI==0){
      int b=m>>8, nn=m&255, h=n>>6, d=n&63;
      float part=__shfl_xor(v,1);
      float c=cosT[(nn<<6)+d], s=sinT[(nn<<6)+d];
      float rot=(d&1)?part:-part;
      out0[(((long)(b*16+h)*256+nn)<<6)+d]=f2bf((v*c+rot*s)*0.125f);
    } else if(EPI==1){
      int b=m>>8, nn=m&255, h=(n>>6)&15, d=n&63;
      if(n<1024){   // uniform per block (tn<8)
        float part=__shfl_xor(v,1);
        float c=cosT[(nn<<6)+d], s=sinT[(nn<<6)+d];
        float rot=(d&1)?part:-part;
        out0[(((long)(b*16+h)*256+nn)<<6)+d]=f2bf(v*c+rot*s);
      }else{
        out1[(((long)(b*16+h)*256+nn)<<6)+d]=f2bf(v);
      }
    } else {
      float o=v+bias[n];
      if(fl) ((float*)dout)[((long)m<<10)+n]=o;
      else   ((short*)dout)[((long)m<<10)+n]=f2bf(o);
    }
  }
}

// ---------------- V transpose: (B,H,N,64) -> (B,H,64,256) -------------------
__global__ void k_vtrans(const short* v, short* vt){
  __shared__ short t[64][65];
  int bh=blockIdx.y, n0=blockIdx.x*64;
  int tid=threadIdx.x;
  const short* src=v+((long)bh*256+n0)*64;
  int n=tid>>2, c=tid&3;
  s16x8 x0=ld16(src+n*64+c*16);
  s16x8 x1=ld16(src+n*64+c*16+8);
  #pragma unroll
  for(int j=0;j<8;j++){ t[c*16+j][n]=x0[j]; t[c*16+8+j][n]=x1[j]; }
  __syncthreads();
  int d=tid>>2, c2=tid&3;
  s16x16 ov;
  #pragma unroll
  for(int j=0;j<16;j++) ov[j]=t[d][c2*16+j];
  *(s16x16*)&vt[((long)bh*64+d)*256+n0+c2*16]=ov;
}

// ---------------- attention: 1 block per (b,h), 4 waves x 64 q-rows ---------
// Swapped QK^T: ST = mfma(K,Q) => D[kv=(l>>4)*4+r][q=l&15]; softmax per q is
// lane-local + 2 shfl_xor. P^T redistributed in-register to the PV B-operand.
// PV: O^T = mfma(VT, P^T) => D[d=(l>>4)*4+r][q=l&15]. LDS-transposed epilogue.
__launch_bounds__(256,2)
__global__ void k_attn(const short* qh, const short* kb, const short* vt, short* out){
  __shared__ __align__(16) short ol[4][64][72];
  int bh=blockIdx.x, b=bh>>4, h=bh&15;
  int tid=threadIdx.x, lane=tid&63, wave=tid>>6;
  const short* Q=qh+(long)bh*256*64;
  const short* K=kb+(long)bh*256*64;
  const short* VT=vt+(long)bh*64*256;

  s16x8 qf[4][2];
  #pragma unroll
  for(int qb=0;qb<4;qb++)
    #pragma unroll
    for(int kk=0;kk<2;kk++)
      qf[qb][kk]=ld16(Q+(wave*64+qb*16+(lane&15))*64+kk*32+(lane>>4)*8);

  f32x4 o[4][4]={};
  float mrow[4]={-INFINITY,-INFINITY,-INFINITY,-INFINITY};
  float srow[4]={0.f,0.f,0.f,0.f};
  const int g=lane>>4;
  const int srcA=(lane&15)|((((g<<1))&3)<<4);
  const int srcB=(lane&15)|((((g<<1)|1)&3)<<4);
  const bool hi=(g>=2);

  for(int kt=0;kt<8;kt++){
    s16x8 kA[2][2];
    #pragma unroll
    for(int f=0;f<2;f++)
      #pragma unroll
      for(int kk=0;kk<2;kk++)
        kA[f][kk]=ld16(K+(kt*32+f*16+(lane&15))*64+kk*32+(lane>>4)*8);
    f32x4 st[2][4]={};
    #pragma unroll
    for(int kk=0;kk<2;kk++)
      #pragma unroll
      for(int f=0;f<2;f++)
        #pragma unroll
        for(int qb=0;qb<4;qb++)
          st[f][qb]=__builtin_amdgcn_mfma_f32_16x16x32_bf16(kA[f][kk],qf[qb][kk],st[f][qb],0,0,0);

    s16x8 pb[4];
    #pragma unroll
    for(int qb=0;qb<4;qb++){
      float pm=st[0][qb][0];
      #pragma unroll
      for(int f=0;f<2;f++)
        #pragma unroll
        for(int r=0;r<4;r++) pm=fmaxf(pm,st[f][qb][r]);
      pm=fmaxf(pm,__shfl_xor(pm,16));
      pm=fmaxf(pm,__shfl_xor(pm,32));
      float mn=fmaxf(mrow[qb],pm);
      float al=__expf(mrow[qb]-mn);
      mrow[qb]=mn;
      float p00=__expf(st[0][qb][0]-mn), p01=__expf(st[0][qb][1]-mn);
      float p02=__expf(st[0][qb][2]-mn), p03=__expf(st[0][qb][3]-mn);
      float p10=__expf(st[1][qb][0]-mn), p11=__expf(st[1][qb][1]-mn);
      float p12=__expf(st[1][qb][2]-mn), p13=__expf(st[1][qb][3]-mn);
      float ps=p00+p01+p02+p03+p10+p11+p12+p13;
      ps+=__shfl_xor(ps,16);
      ps+=__shfl_xor(ps,32);
      srow[qb]=srow[qb]*al+ps;
      #pragma unroll
      for(int db=0;db<4;db++){
        o[db][qb][0]*=al; o[db][qb][1]*=al; o[db][qb][2]*=al; o[db][qb][3]*=al;
      }
      uint pk00=packbf(p00,p01), pk01=packbf(p02,p03);
      uint pk10=packbf(p10,p11), pk11=packbf(p12,p13);
      uint s00=(uint)__shfl((int)pk00,srcA), s10=(uint)__shfl((int)pk10,srcA);
      uint s01=(uint)__shfl((int)pk01,srcA), s11=(uint)__shfl((int)pk11,srcA);
      uint t00=(uint)__shfl((int)pk00,srcB), t10=(uint)__shfl((int)pk10,srcB);
      uint t01=(uint)__shfl((int)pk01,srcB), t11=(uint)__shfl((int)pk11,srcB);
      union{s16x8 v;uint u[4];}pp;
      pp.u[0]=hi?s10:s00;
      pp.u[1]=hi?s11:s01;
      pp.u[2]=hi?t10:t00;
      pp.u[3]=hi?t11:t01;
      pb[qb]=pp.v;
    }
    s16x8 vA[4];
    #pragma unroll
    for(int db=0;db<4;db++)
      vA[db]=ld16(VT+(db*16+(lane&15))*256+kt*32+(lane>>4)*8);
    #pragma unroll
    for(int db=0;db<4;db++)
      #pragma unroll
      for(int qb=0;qb<4;qb++)
        o[db][qb]=__builtin_amdgcn_mfma_f32_16x16x32_bf16(vA[db],pb[qb],o[db][qb],0,0,0);
  }

  #pragma unroll
  for(int db=0;db<4;db++)
    #pragma unroll
    for(int qb=0;qb<4;qb++)
      #pragma unroll
      for(int r=0;r<4;r++){
        int d=db*16+(lane>>4)*4+r;
        int q=qb*16+(lane&15);
        ol[wave][q][d]=f2bf(o[db][qb][r]/srow[qb]);
      }
  __syncthreads();
  #pragma unroll
  for(int it=0;it<8;it++){
    int q=wave*64+it*8+(lane>>3);
    int cc=lane&7;
    s16x8 x=*(const s16x8*)&ol[wave][it*8+(lane>>3)][cc*8];
    *(s16x8*)&out[((long)(b*256+q)<<10)+h*64+cc*8]=x;
  }
}

// ---------------- host ------------------------------------------------------
extern "C" void kernel_launch(void* const* d_in, const int* in_sizes, int n_in,
                              void* d_out, int out_size, void* d_ws, size_t ws_size,
                              hipStream_t stream){
  const long M=16384;
  char* ws=(char*)d_ws;
  size_t off=0;
  auto alloc=[&](size_t b){ void* p=ws+off; off+=(b+255)&~(size_t)255; return p; };
  int*   flag =(int*)  alloc(256);
  float* cosT =(float*)alloc(256*64*4);
  float* sinT =(float*)alloc(256*64*4);
  float* biasF=(float*)alloc(1024*4);
  short* qbf  =(short*)alloc((size_t)M*1024*2);   // reused as attn_out
  short* kvbf =(short*)alloc((size_t)M*768*2);
  short* WqT  =(short*)alloc((size_t)1024*1024*2);
  short* WkvT =(short*)alloc((size_t)2048*768*2);
  short* WpT  =(short*)alloc((size_t)1024*1024*2);
  short* qhB  =(short*)alloc((size_t)16777216*2);
  short* kbuf =(short*)alloc((size_t)16777216*2);
  short* vbuf =(short*)alloc((size_t)16777216*2);
  short* vtb  =(short*)alloc((size_t)16777216*2);

  k_detect<<<1,256,0,stream>>>((const uint*)d_in[0],flag);
  k_tables<<<64,256,0,stream>>>(cosT,sinT);
  k_bias<<<4,256,0,stream>>>(d_in[5],biasF,flag);
  k_convert<<<2048,256,0,stream>>>(d_in[0],qbf,(long)M*1024/8,flag);
  k_convert<<<2048,256,0,stream>>>(d_in[1],kvbf,(long)M*768/8,flag);
  k_transpose<<<512,256,0,stream>>>(d_in[2],WqT,1024,1024,flag);
  k_transpose<<<768,256,0,stream>>>(d_in[3],WkvT,768,2048,flag);
  k_transpose<<<512,256,0,stream>>>(d_in[4],WpT,1024,1024,flag);

  k_gemm<0><<<dim3(8,128),256,0,stream>>>(qbf ,WqT ,1024,qhB ,nullptr,cosT,sinT,biasF,flag,nullptr);
  k_gemm<1><<<dim3(16,128),256,0,stream>>>(kvbf,WkvT, 768,kbuf,vbuf   ,cosT,sinT,biasF,flag,nullptr);
  k_vtrans<<<dim3(4,1024),256,0,stream>>>(vbuf,vtb);
  k_attn<<<1024,256,0,stream>>>(qhB,kbuf,vtb,qbf);
  k_gemm<2><<<dim3(8,128),256,0,stream>>>(qbf ,WpT ,1024,nullptr,nullptr,cosT,sinT,biasF,flag,d_out);
}

// Round 2
// 310.584 us; speedup vs baseline: 1.0980x; 1.0980x over previous
//
#include <hip/hip_runtime.h>
#include <hip/hip_bf16.h>
#include <math.h>

// CrossAttention fused pipeline, bf16 MFMA everywhere.
// B=64, N=256, C=1024, H=16, hd=64, sem=768, M=B*N=16384.
// R2: GEMM = 2-phase double-buffered pipeline (T3-min), conflict-free LDS
// swizzle S(row)=(row>>1)&3, V written pre-transposed in EPI1 (vtrans fused).

typedef unsigned int uint;
typedef __attribute__((ext_vector_type(4)))  short s16x4;
typedef __attribute__((ext_vector_type(8)))  short s16x8;
typedef __attribute__((ext_vector_type(4)))  float f32x4;

#define AS1 __attribute__((address_space(1)))
#define AS3 __attribute__((address_space(3)))

__device__ __forceinline__ short f2bf(float x){
  union{float f;uint u;}v; v.f=x;
  return (short)((v.u + 0x7FFFu + ((v.u>>16)&1u))>>16);   // RNE
}
__device__ __forceinline__ float bf2f(short s){
  union{float f;uint u;}v; v.u=((uint)(unsigned short)s)<<16; return v.f;
}
__device__ __forceinline__ uint packbf(float a,float b){
  return (uint)(unsigned short)f2bf(a) | ((uint)(unsigned short)f2bf(b)<<16);
}
__device__ __forceinline__ void gl_lds16(const void* g, void* l){
  __builtin_amdgcn_global_load_lds((const AS1 uint*)g, (AS3 uint*)l, 16, 0, 0);
}
__device__ __forceinline__ s16x8 ld16(const short* p){ return *(const s16x8*)p; }

// ---------------- dtype detection -------------------------------------------
__global__ void k_detect(const uint* q, int* flag){
  __shared__ int cnt;
  if(threadIdx.x==0) cnt=0;
  __syncthreads();
  int c=0;
  for(int i=threadIdx.x;i<4096;i+=256){
    uint e=(q[i]>>7)&0xFFu;
    if(e>=120u && e<=130u) c++;
  }
  atomicAdd(&cnt,c);
  __syncthreads();
  if(threadIdx.x==0) *flag = (cnt>2048)?0:1;
}

// ---------------- conversions -----------------------------------------------
__global__ void k_convert(const void* src, short* dst, long n8, const int* flag){
  int f=*flag;
  long stride=(long)gridDim.x*blockDim.x;
  for(long i=(long)blockIdx.x*blockDim.x+threadIdx.x;i<n8;i+=stride){
    s16x8 o;
    if(f){
      const float4* s=(const float4*)src;
      float4 a=s[i*2], b=s[i*2+1];
      o[0]=f2bf(a.x);o[1]=f2bf(a.y);o[2]=f2bf(a.z);o[3]=f2bf(a.w);
      o[4]=f2bf(b.x);o[5]=f2bf(b.y);o[6]=f2bf(b.z);o[7]=f2bf(b.w);
    }else{
      o=((const s16x8*)src)[i];
    }
    ((s16x8*)dst)[i]=o;
  }
}

// W (K x Nn) row-major -> WT (Nn x K) row-major (bf16).
__global__ void k_transpose(const void* W, short* WT, int K, int Nn, const int* flag){
  int f=*flag;
  long total=(long)Nn*(K/8);
  long stride=(long)gridDim.x*blockDim.x;
  for(long idx=(long)blockIdx.x*blockDim.x+threadIdx.x;idx<total;idx+=stride){
    int n=(int)(idx%Nn); int kc=(int)(idx/Nn); int k0=kc*8;
    s16x8 o;
    #pragma unroll
    for(int j=0;j<8;j++){
      o[j]= f ? f2bf(((const float*)W)[(long)(k0+j)*Nn+n])
              : ((const short*)W)[(long)(k0+j)*Nn+n];
    }
    *(s16x8*)&WT[(long)n*K+k0]=o;
  }
}

// RoPE tables, double precision to match numpy float64->float32.
__global__ void k_tables(float* cosT, float* sinT){
  int t=blockIdx.x*blockDim.x+threadIdx.x;
  if(t>=256*64) return;
  int n=t>>6, d=t&63;
  int i=n>>4, j=n&15;
  int p=(d&31)>>1;
  double fr=pow(10000.0, -(double)(2*p)/32.0);
  double tt=(d<32)?(double)i:(double)j;
  double a=tt*fr;
  cosT[t]=(float)cos(a);
  sinT[t]=(float)sin(a);
}

__global__ void k_bias(const void* b, float* bo, const int* flag){
  int t=blockIdx.x*blockDim.x+threadIdx.x;
  if(t<1024) bo[t] = (*flag)? ((const float*)b)[t] : bf2f(((const short*)b)[t]);
}

// ---------------- GEMM: C[M,N] = A[M,K] * BT[N,K]^T, fused epilogues --------
// EPI 0: RoPE+scale -> qh (B,H,N,64) bf16
// EPI 1: n<1024: RoPE -> k (B,H,N,64); else: v transposed -> (B,H,64,256)
// EPI 2: +bias -> d_out (fp32 or bf16 per flag)
// 2-phase pipeline: STAGE(next) issued before ds_read+MFMA(cur), one barrier
// per K-step. LDS swizzle: slot c of row r holds global chunk c^((r>>1)&3)
// -> ds_read_b128 across 16 consecutive rows is 2-way max (free, m136).
template<int EPI>
__launch_bounds__(256,2)
__global__ void k_gemm(const short* A, const short* BT, int Kdim,
                       short* out0, short* out1,
                       const float* cosT, const float* sinT,
                       const float* bias, const int* flag, void* dout){
  __shared__ __align__(16) short Alds[2][128*32];
  __shared__ __align__(16) short Blds[2][128*32];
  const int tid=threadIdx.x, lane=tid&63;
  const int wave=tid>>6, wm=wave>>1, wn=wave&1;
  const int tn=blockIdx.x, tm=blockIdx.y;
  const int fl=*flag;
  f32x4 acc[4][4]={};
  const short* Ag=A+(long)tm*128*Kdim;
  const short* Bg=BT+(long)tn*128*Kdim;
  const int row0=tid>>2, c0=tid&3;
  const int row1=64+row0;
  const int sw0=(c0^((row0>>1)&3))*8;
  const int sw1=(c0^((row1>>1)&3))*8;

  #define STAGE(bufsel,kb) do{                                        \
    gl_lds16(Ag+(long)row0*Kdim+(kb)+sw0, &Alds[bufsel][tid*8]);      \
    gl_lds16(Ag+(long)row1*Kdim+(kb)+sw1, &Alds[bufsel][(256+tid)*8]);\
    gl_lds16(Bg+(long)row0*Kdim+(kb)+sw0, &Blds[bufsel][tid*8]);      \
    gl_lds16(Bg+(long)row1*Kdim+(kb)+sw1, &Blds[bufsel][(256+tid)*8]);\
  }while(0)

  const int nt=Kdim>>5;
  STAGE(0,0);
  __syncthreads();
  int cur=0;
  for(int t=0;t<nt;t++){
    if(t+1<nt) STAGE(cur^1,(t+1)*32);
    s16x8 af[4], bfr[4];
    #pragma unroll
    for(int rb=0;rb<4;rb++){
      int ar=wm*64+rb*16+(lane&15);
      af[rb]=*(const s16x8*)&Alds[cur][ar*32+(((lane>>4)^((ar>>1)&3))*8)];
    }
    #pragma unroll
    for(int cb=0;cb<4;cb++){
      int br=wn*64+cb*16+(lane&15);
      bfr[cb]=*(const s16x8*)&Blds[cur][br*32+(((lane>>4)^((br>>1)&3))*8)];
    }
    #pragma unroll
    for(int rb=0;rb<4;rb++)
      #pragma unroll
      for(int cb=0;cb<4;cb++)
        acc[rb][cb]=__builtin_amdgcn_mfma_f32_16x16x32_bf16(af[rb],bfr[cb],acc[rb][cb],0,0,0);
    __syncthreads();
    cur^=1;
  }
  #undef STAGE

  const int mbase=tm*128+wm*64, nbase=tn*128+wn*64;
  const int g=lane>>4, li=lane&15;
  #pragma unroll
  for(int rb=0;rb<4;rb++)
  #pragma unroll
  for(int cb=0;cb<4;cb++){
    const int m0=mbase+rb*16+g*4;
    const int n=nbase+cb*16+li;
    if(EPI==0){
      #pragma unroll
      for(int r=0;r<4;r++){
        float v=acc[rb][cb][r];
        int m=m0+r; int b=m>>8, nn=m&255, h=n>>6, d=n&63;
        float part=__shfl_xor(v,1);
        float c=cosT[(nn<<6)+d], s=sinT[(nn<<6)+d];
        float rot=(d&1)?part:-part;
        out0[(((long)(b*16+h)*256+nn)<<6)+d]=f2bf((v*c+rot*s)*0.125f);
      }
    } else if(EPI==1){
      if(n<1024){   // uniform per block (tn<8): k with RoPE
        #pragma unroll
        for(int r=0;r<4;r++){
          float v=acc[rb][cb][r];
          int m=m0+r; int b=m>>8, nn=m&255, h=(n>>6)&15, d=n&63;
          float part=__shfl_xor(v,1);
          float c=cosT[(nn<<6)+d], s=sinT[(nn<<6)+d];
          float rot=(d&1)?part:-part;
          out0[(((long)(b*16+h)*256+nn)<<6)+d]=f2bf(v*c+rot*s);
        }
      }else{        // v, written pre-transposed (B,H,64,256)
        int h=(n>>6)&15, d=n&63;
        int b=m0>>8, nn0=m0&255;
        s16x4 pk;
        #pragma unroll
        for(int r=0;r<4;r++) pk[r]=f2bf(acc[rb][cb][r]);
        *(s16x4*)&out1[(((long)(b*16+h)*64+d)<<8)+nn0]=pk;
      }
    } else {
      #pragma unroll
      for(int r=0;r<4;r++){
        float o=acc[rb][cb][r]+bias[n];
        long idx=((long)(m0+r)<<10)+n;
        if(fl) ((float*)dout)[idx]=o;
        else   ((short*)dout)[idx]=f2bf(o);
      }
    }
  }
}

// ---------------- attention: 1 block per (b,h), 4 waves x 64 q-rows ---------
// Swapped QK^T: ST = mfma(K,Q) => D[kv=(l>>4)*4+r][q=l&15]; softmax per q is
// lane-local + 2 shfl_xor. P^T redistributed in-register to the PV B-operand.
// PV: O^T = mfma(VT, P^T) => D[d=(l>>4)*4+r][q=l&15]. LDS-transposed epilogue.
__launch_bounds__(256,2)
__global__ void k_attn(const short* qh, const short* kb, const short* vt, short* out){
  __shared__ __align__(16) short ol[4][64][72];
  int bh=blockIdx.x, b=bh>>4, h=bh&15;
  int tid=threadIdx.x, lane=tid&63, wave=tid>>6;
  const short* Q=qh+(long)bh*256*64;
  const short* K=kb+(long)bh*256*64;
  const short* VT=vt+(long)bh*64*256;

  s16x8 qf[4][2];
  #pragma unroll
  for(int qb=0;qb<4;qb++)
    #pragma unroll
    for(int kk=0;kk<2;kk++)
      qf[qb][kk]=ld16(Q+(wave*64+qb*16+(lane&15))*64+kk*32+(lane>>4)*8);

  f32x4 o[4][4]={};
  float mrow[4]={-INFINITY,-INFINITY,-INFINITY,-INFINITY};
  float srow[4]={0.f,0.f,0.f,0.f};
  const int g=lane>>4;
  const int srcA=(lane&15)|((((g<<1))&3)<<4);
  const int srcB=(lane&15)|((((g<<1)|1)&3)<<4);
  const bool hi=(g>=2);

  for(int kt=0;kt<8;kt++){
    s16x8 kA[2][2];
    #pragma unroll
    for(int f=0;f<2;f++)
      #pragma unroll
      for(int kk=0;kk<2;kk++)
        kA[f][kk]=ld16(K+(kt*32+f*16+(lane&15))*64+kk*32+(lane>>4)*8);
    f32x4 st[2][4]={};
    #pragma unroll
    for(int kk=0;kk<2;kk++)
      #pragma unroll
      for(int f=0;f<2;f++)
        #pragma unroll
        for(int qb=0;qb<4;qb++)
          st[f][qb]=__builtin_amdgcn_mfma_f32_16x16x32_bf16(kA[f][kk],qf[qb][kk],st[f][qb],0,0,0);

    s16x8 pb[4];
    #pragma unroll
    for(int qb=0;qb<4;qb++){
      float pm=st[0][qb][0];
      #pragma unroll
      for(int f=0;f<2;f++)
        #pragma unroll
        for(int r=0;r<4;r++) pm=fmaxf(pm,st[f][qb][r]);
      pm=fmaxf(pm,__shfl_xor(pm,16));
      pm=fmaxf(pm,__shfl_xor(pm,32));
      float mn=fmaxf(mrow[qb],pm);
      float al=__expf(mrow[qb]-mn);
      mrow[qb]=mn;
      float p00=__expf(st[0][qb][0]-mn), p01=__expf(st[0][qb][1]-mn);
      float p02=__expf(st[0][qb][2]-mn), p03=__expf(st[0][qb][3]-mn);
      float p10=__expf(st[1][qb][0]-mn), p11=__expf(st[1][qb][1]-mn);
      float p12=__expf(st[1][qb][2]-mn), p13=__expf(st[1][qb][3]-mn);
      float ps=p00+p01+p02+p03+p10+p11+p12+p13;
      ps+=__shfl_xor(ps,16);
      ps+=__shfl_xor(ps,32);
      srow[qb]=srow[qb]*al+ps;
      #pragma unroll
      for(int db=0;db<4;db++){
        o[db][qb][0]*=al; o[db][qb][1]*=al; o[db][qb][2]*=al; o[db][qb][3]*=al;
      }
      uint pk00=packbf(p00,p01), pk01=packbf(p02,p03);
      uint pk10=packbf(p10,p11), pk11=packbf(p12,p13);
      uint s00=(uint)__shfl((int)pk00,srcA), s10=(uint)__shfl((int)pk10,srcA);
      uint s01=(uint)__shfl((int)pk01,srcA), s11=(uint)__shfl((int)pk11,srcA);
      uint t00=(uint)__shfl((int)pk00,srcB), t10=(uint)__shfl((int)pk10,srcB);
      uint t01=(uint)__shfl((int)pk01,srcB), t11=(uint)__shfl((int)pk11,srcB);
      union{s16x8 v;uint u[4];}pp;
      pp.u[0]=hi?s10:s00;
      pp.u[1]=hi?s11:s01;
      pp.u[2]=hi?t10:t00;
      pp.u[3]=hi?t11:t01;
      pb[qb]=pp.v;
    }
    s16x8 vA[4];
    #pragma unroll
    for(int db=0;db<4;db++)
      vA[db]=ld16(VT+(db*16+(lane&15))*256+kt*32+(lane>>4)*8);
    #pragma unroll
    for(int db=0;db<4;db++)
      #pragma unroll
      for(int qb=0;qb<4;qb++)
        o[db][qb]=__builtin_amdgcn_mfma_f32_16x16x32_bf16(vA[db],pb[qb],o[db][qb],0,0,0);
  }

  #pragma unroll
  for(int db=0;db<4;db++)
    #pragma unroll
    for(int qb=0;qb<4;qb++)
      #pragma unroll
      for(int r=0;r<4;r++){
        int d=db*16+(lane>>4)*4+r;
        int q=qb*16+(lane&15);
        ol[wave][q][d]=f2bf(o[db][qb][r]/srow[qb]);
      }
  __syncthreads();
  #pragma unroll
  for(int it=0;it<8;it++){
    int q=wave*64+it*8+(lane>>3);
    int cc=lane&7;
    s16x8 x=*(const s16x8*)&ol[wave][it*8+(lane>>3)][cc*8];
    *(s16x8*)&out[((long)(b*256+q)<<10)+h*64+cc*8]=x;
  }
}

// ---------------- host ------------------------------------------------------
extern "C" void kernel_launch(void* const* d_in, const int* in_sizes, int n_in,
                              void* d_out, int out_size, void* d_ws, size_t ws_size,
                              hipStream_t stream){
  const long M=16384;
  char* ws=(char*)d_ws;
  size_t off=0;
  auto alloc=[&](size_t b){ void* p=ws+off; off+=(b+255)&~(size_t)255; return p; };
  int*   flag =(int*)  alloc(256);
  float* cosT =(float*)alloc(256*64*4);
  float* sinT =(float*)alloc(256*64*4);
  float* biasF=(float*)alloc(1024*4);
  short* qbf  =(short*)alloc((size_t)M*1024*2);   // reused as attn_out
  short* kvbf =(short*)alloc((size_t)M*768*2);
  short* WqT  =(short*)alloc((size_t)1024*1024*2);
  short* WkvT =(short*)alloc((size_t)2048*768*2);
  short* WpT  =(short*)alloc((size_t)1024*1024*2);
  short* qhB  =(short*)alloc((size_t)16777216*2);
  short* kbuf =(short*)alloc((size_t)16777216*2);
  short* vtb  =(short*)alloc((size_t)16777216*2);

  k_detect<<<1,256,0,stream>>>((const uint*)d_in[0],flag);
  k_tables<<<64,256,0,stream>>>(cosT,sinT);
  k_bias<<<4,256,0,stream>>>(d_in[5],biasF,flag);
  k_convert<<<2048,256,0,stream>>>(d_in[0],qbf,(long)M*1024/8,flag);
  k_convert<<<2048,256,0,stream>>>(d_in[1],kvbf,(long)M*768/8,flag);
  k_transpose<<<512,256,0,stream>>>(d_in[2],WqT,1024,1024,flag);
  k_transpose<<<768,256,0,stream>>>(d_in[3],WkvT,768,2048,flag);
  k_transpose<<<512,256,0,stream>>>(d_in[4],WpT,1024,1024,flag);

  k_gemm<0><<<dim3(8,128),256,0,stream>>>(qbf ,WqT ,1024,qhB ,nullptr,cosT,sinT,biasF,flag,nullptr);
  k_gemm<1><<<dim3(16,128),256,0,stream>>>(kvbf,WkvT, 768,kbuf,vtb    ,cosT,sinT,biasF,flag,nullptr);
  k_attn<<<1024,256,0,stream>>>(qhB,kbuf,vtb,qbf);
  k_gemm<2><<<dim3(8,128),256,0,stream>>>(qbf ,WpT ,1024,nullptr,nullptr,cosT,sinT,biasF,flag,d_out);
}

// Round 3
// 270.834 us; speedup vs baseline: 1.2591x; 1.1468x over previous
//
#include <hip/hip_runtime.h>
#include <hip/hip_bf16.h>
#include <math.h>

// CrossAttention fused pipeline, bf16 MFMA everywhere.
// B=64, N=256, C=1024, H=16, hd=64, sem=768, M=B*N=16384.
// R3: GEMM -> 256x256x64 8-phase schedule (T2 swizzle + T3/T4 counted vmcnt +
// T5 setprio), 8 waves (2Mx4N), 128KiB LDS, XCD-swizzled block ids.

typedef unsigned int uint;
typedef __attribute__((ext_vector_type(4)))  short s16x4;
typedef __attribute__((ext_vector_type(8)))  short s16x8;
typedef __attribute__((ext_vector_type(16))) short s16x16;
typedef __attribute__((ext_vector_type(4)))  float f32x4;

#define AS1 __attribute__((address_space(1)))
#define AS3 __attribute__((address_space(3)))

__device__ __forceinline__ short f2bf(float x){
  union{float f;uint u;}v; v.f=x;
  return (short)((v.u + 0x7FFFu + ((v.u>>16)&1u))>>16);   // RNE
}
__device__ __forceinline__ float bf2f(short s){
  union{float f;uint u;}v; v.u=((uint)(unsigned short)s)<<16; return v.f;
}
__device__ __forceinline__ uint packbf(float a,float b){
  return (uint)(unsigned short)f2bf(a) | ((uint)(unsigned short)f2bf(b)<<16);
}
__device__ __forceinline__ void gl_lds16(const void* g, void* l){
  __builtin_amdgcn_global_load_lds((const AS1 uint*)g, (AS3 uint*)l, 16, 0, 0);
}
__device__ __forceinline__ s16x8 ld16(const short* p){ return *(const s16x8*)p; }

// ---------------- dtype detection -------------------------------------------
__global__ void k_detect(const uint* q, int* flag){
  __shared__ int cnt;
  if(threadIdx.x==0) cnt=0;
  __syncthreads();
  int c=0;
  for(int i=threadIdx.x;i<4096;i+=256){
    uint e=(q[i]>>7)&0xFFu;
    if(e>=120u && e<=130u) c++;
  }
  atomicAdd(&cnt,c);
  __syncthreads();
  if(threadIdx.x==0) *flag = (cnt>2048)?0:1;
}

// ---------------- conversions -----------------------------------------------
__global__ void k_convert(const void* src, short* dst, long n8, const int* flag){
  int f=*flag;
  long stride=(long)gridDim.x*blockDim.x;
  for(long i=(long)blockIdx.x*blockDim.x+threadIdx.x;i<n8;i+=stride){
    s16x8 o;
    if(f){
      const float4* s=(const float4*)src;
      float4 a=s[i*2], b=s[i*2+1];
      o[0]=f2bf(a.x);o[1]=f2bf(a.y);o[2]=f2bf(a.z);o[3]=f2bf(a.w);
      o[4]=f2bf(b.x);o[5]=f2bf(b.y);o[6]=f2bf(b.z);o[7]=f2bf(b.w);
    }else{
      o=((const s16x8*)src)[i];
    }
    ((s16x8*)dst)[i]=o;
  }
}

// W (K x Nn) row-major -> WT (Nn x K) row-major (bf16).
__global__ void k_transpose(const void* W, short* WT, int K, int Nn, const int* flag){
  int f=*flag;
  long total=(long)Nn*(K/8);
  long stride=(long)gridDim.x*blockDim.x;
  for(long idx=(long)blockIdx.x*blockDim.x+threadIdx.x;idx<total;idx+=stride){
    int n=(int)(idx%Nn); int kc=(int)(idx/Nn); int k0=kc*8;
    s16x8 o;
    #pragma unroll
    for(int j=0;j<8;j++){
      o[j]= f ? f2bf(((const float*)W)[(long)(k0+j)*Nn+n])
              : ((const short*)W)[(long)(k0+j)*Nn+n];
    }
    *(s16x8*)&WT[(long)n*K+k0]=o;
  }
}

// RoPE tables, double precision to match numpy float64->float32.
__global__ void k_tables(float* cosT, float* sinT){
  int t=blockIdx.x*blockDim.x+threadIdx.x;
  if(t>=256*64) return;
  int n=t>>6, d=t&63;
  int i=n>>4, j=n&15;
  int p=(d&31)>>1;
  double fr=pow(10000.0, -(double)(2*p)/32.0);
  double tt=(d<32)?(double)i:(double)j;
  double a=tt*fr;
  cosT[t]=(float)cos(a);
  sinT[t]=(float)sin(a);
}

__global__ void k_bias(const void* b, float* bo, const int* flag){
  int t=blockIdx.x*blockDim.x+threadIdx.x;
  if(t<1024) bo[t] = (*flag)? ((const float*)b)[t] : bf2f(((const short*)b)[t]);
}

// ---------------- 8-phase GEMM: C[M,N]=A[M,K]*BT[N,K]^T, fused epilogues ----
// Tile 256x256, BK=64, 512 threads = 8 waves (wm=wave>>2, wn=wave&3), each
// wave owns 128x64 output (8x4 frags of 16x16). LDS = 2dbuf x {A,B} x 2half
// x (128x64 bf16) = 128 KiB. Swizzle: 16B slot s of row r holds global chunk
// s ^ ((r>>1)&7)  (involution; applied on pre-swizzled global src + ds_read).
// Stage stream per K-tile: [B-h0, B-h1, A-h0, A-h1]; per phase 1 half-tile
// (2 x gl_lds16/thread). Retire/issue safety (barrier between all pairs):
//   buf read at p1-4: B region last ds_read @p2, A @p3;
//   stages into it: B@p3,p4, A@p5,p6.  (mirror for p5-8 buf: B@p7,p8, A@np1,np2)
// vmcnt(4) at p4: all but last 2 half-tiles landed => tile t+1 complete before
// its p5 ds_reads. vmcnt(4) at p8 => tile t+2 complete before next-p1 reads.
// Tail stages wrap modulo NT into retired regions (memory-safe, discarded).
#define BAR   __builtin_amdgcn_s_barrier()
#define LGKM0 asm volatile("s_waitcnt lgkmcnt(0)" ::: "memory")
#define VMC4  asm volatile("s_waitcnt vmcnt(4)" ::: "memory")
#define PRIO1 __builtin_amdgcn_s_setprio(1)
#define PRIO0 __builtin_amdgcn_s_setprio(0)

#define MM(H,V,BR) do{ \
  _Pragma("unroll") for(int ks_=0;ks_<2;ks_++){ \
    _Pragma("unroll") for(int mf_=0;mf_<4;mf_++){ \
      _Pragma("unroll") for(int nf_=0;nf_<2;nf_++){ \
        acc[(H)*4+mf_][(V)*2+nf_]=__builtin_amdgcn_mfma_f32_16x16x32_bf16( \
          aR[mf_][ks_],BR[nf_][ks_],acc[(H)*4+mf_][(V)*2+nf_],0,0,0); \
  }}} }while(0)

#define HALFIT(BUF,TA,TB) do{ \
  const short* RA=&lds[BUF][0][wm][0]; \
  const short* RB=&lds[BUF][1][0][0]; \
  ldA(RA,0,aR); ldB(RB,0,bR0); stage(0,0,TA); \
  BAR; LGKM0; PRIO1; MM(0,0,bR0); PRIO0; BAR; \
  ldB(RB,1,bR1); stage(0,1,TA); \
  BAR; LGKM0; PRIO1; MM(0,1,bR1); PRIO0; BAR; \
  ldA(RA,1,aR); stage(1,0,TB); \
  BAR; LGKM0; PRIO1; MM(1,1,bR1); PRIO0; BAR; \
  stage(1,1,TB); \
  BAR; PRIO1; MM(1,0,bR0); PRIO0; VMC4; BAR; \
}while(0)

template<int EPI>
__launch_bounds__(512,2)
__global__ void k_gemm8(const short* __restrict__ A, const short* __restrict__ BT,
                        const int Kdim, const int lgN,
                        short* __restrict__ out0, short* __restrict__ out1,
                        const float* __restrict__ cosT, const float* __restrict__ sinT,
                        const float* __restrict__ bias, const int* __restrict__ flag,
                        void* __restrict__ dout){
  __shared__ __align__(16) short lds[2][2][2][8192];  // [dbuf][A/B][half][128*64]
  const int tid=threadIdx.x, lane=tid&63, wave=tid>>6;
  const int li=lane&15, gq=lane>>4;
  const int wm=wave>>2, wn=wave&3;
  // XCD-aware bijective block swizzle (nwg % 8 == 0 for all our grids)
  const int nwg=gridDim.x, cpx=nwg>>3;
  const int wg=((int)blockIdx.x&7)*cpx+((int)blockIdx.x>>3);
  const int tn=wg&((1<<lgN)-1), tm=wg>>lgN;
  const int NT=Kdim>>6;
  const short* Ag=A+(long)tm*256*Kdim;
  const short* Bg=BT+(long)tn*256*Kdim;
  const int fl=(EPI==2)? *flag : 0;
  f32x4 acc[8][4]={};
  s16x8 aR[4][2], bR0[2][2], bR1[2][2];

  auto stage=[&](int op,int hf,int kt){
    int ktw=(kt>=NT)?kt-NT:kt;               // tail wrap, memory-safe
    const short* G=(op? Bg:Ag)+((long)(hf*128))*Kdim+ktw*64;
    short* R=&lds[kt&1][op][hf][0];          // NT even -> parity preserved
    #pragma unroll
    for(int l=0;l<2;l++){
      int lr=l*64+wave*8+(lane>>3);
      int c=(lane&7)^((lr>>1)&7);            // pre-swizzled global source
      gl_lds16(G+(long)lr*Kdim+c*8, R+l*4096+wave*512+lane*8);
    }
  };
  auto ldA=[&](const short* R,int h,s16x8 (&a)[4][2]){
    #pragma unroll
    for(int mf=0;mf<4;mf++){
      int lr=(h*4+mf)*16+li;
      int sw=(lr>>1)&7;
      #pragma unroll
      for(int ks=0;ks<2;ks++){
        int slot=(ks*4+gq)^sw;
        a[mf][ks]=*(const s16x8*)&R[lr*64+slot*8];
      }
    }
  };
  auto ldB=[&](const short* R0,int v,s16x8 (&b)[2][2]){
    #pragma unroll
    for(int nf=0;nf<2;nf++){
      int row=wn*64+(v*2+nf)*16+li;          // 0..255 across B halves
      const short* R=R0+(row>>7)*8192;
      int lr=row&127;
      int sw=(lr>>1)&7;
      #pragma unroll
      for(int ks=0;ks<2;ks++){
        int slot=(ks*4+gq)^sw;
        b[nf][ks]=*(const s16x8*)&R[lr*64+slot*8];
      }
    }
  };

  // prologue: T0.B, T0.A, T1.B staged (12 loads); wait all but last 4 -> T0 in
  stage(1,0,0); stage(1,1,0); stage(0,0,0); stage(0,1,0);
  stage(1,0,1); stage(1,1,1);
  VMC4;
  BAR;

  for(int t=0;t<NT;t+=2){
    HALFIT(0, t+1, t+2);
    HALFIT(1, t+2, t+3);
  }

  // ---------------- epilogue -------------------------------------------------
  const int mb=tm*256+wm*128, nb=tn*256+wn*64;
  #pragma unroll
  for(int mf=0;mf<8;mf++)
  #pragma unroll
  for(int nf=0;nf<4;nf++){
    const int m0=mb+mf*16+gq*4;
    const int n=nb+nf*16+li;
    if(EPI==0){
      #pragma unroll
      for(int r=0;r<4;r++){
        float v=acc[mf][nf][r];
        int m=m0+r, b=m>>8, nn=m&255, h=n>>6, d=n&63;
        float part=__shfl_xor(v,1);
        float c=cosT[(nn<<6)+d], s=sinT[(nn<<6)+d];
        float rot=(d&1)?part:-part;
        out0[(((long)(b*16+h)*256+nn)<<6)+d]=f2bf((v*c+rot*s)*0.125f);
      }
    } else if(EPI==1){
      if(n<1024){   // uniform per block (tn<4): K-head with RoPE
        #pragma unroll
        for(int r=0;r<4;r++){
          float v=acc[mf][nf][r];
          int m=m0+r, b=m>>8, nn=m&255, h=(n>>6)&15, d=n&63;
          float part=__shfl_xor(v,1);
          float c=cosT[(nn<<6)+d], s=sinT[(nn<<6)+d];
          float rot=(d&1)?part:-part;
          out0[(((long)(b*16+h)*256+nn)<<6)+d]=f2bf(v*c+rot*s);
        }
      }else{        // V, written pre-transposed (B,H,64,256)
        int h=(n>>6)&15, d=n&63, b=m0>>8, nn0=m0&255;
        s16x4 pk;
        #pragma unroll
        for(int r=0;r<4;r++) pk[r]=f2bf(acc[mf][nf][r]);
        *(s16x4*)&out1[(((long)(b*16+h)*64+d)<<8)+nn0]=pk;
      }
    } else {
      #pragma unroll
      for(int r=0;r<4;r++){
        float o=acc[mf][nf][r]+bias[n];
        long idx=((long)(m0+r)<<10)+n;
        if(fl) ((float*)dout)[idx]=o;
        else   ((short*)dout)[idx]=f2bf(o);
      }
    }
  }
}

// ---------------- attention: 1 block per (b,h), 4 waves x 64 q-rows ---------
// Swapped QK^T: ST = mfma(K,Q) => D[kv=(l>>4)*4+r][q=l&15]; softmax per q is
// lane-local + 2 shfl_xor. P^T redistributed in-register to the PV B-operand.
// PV: O^T = mfma(VT, P^T) => D[d=(l>>4)*4+r][q=l&15]. LDS-transposed epilogue.
__launch_bounds__(256,2)
__global__ void k_attn(const short* qh, const short* kb, const short* vt, short* out){
  __shared__ __align__(16) short ol[4][64][72];
  int bh=blockIdx.x, b=bh>>4, h=bh&15;
  int tid=threadIdx.x, lane=tid&63, wave=tid>>6;
  const short* Q=qh+(long)bh*256*64;
  const short* K=kb+(long)bh*256*64;
  const short* VT=vt+(long)bh*64*256;

  s16x8 qf[4][2];
  #pragma unroll
  for(int qb=0;qb<4;qb++)
    #pragma unroll
    for(int kk=0;kk<2;kk++)
      qf[qb][kk]=ld16(Q+(wave*64+qb*16+(lane&15))*64+kk*32+(lane>>4)*8);

  f32x4 o[4][4]={};
  float mrow[4]={-INFINITY,-INFINITY,-INFINITY,-INFINITY};
  float srow[4]={0.f,0.f,0.f,0.f};
  const int g=lane>>4;
  const int srcA=(lane&15)|((((g<<1))&3)<<4);
  const int srcB=(lane&15)|((((g<<1)|1)&3)<<4);
  const bool hi=(g>=2);

  for(int kt=0;kt<8;kt++){
    s16x8 kA[2][2];
    #pragma unroll
    for(int f=0;f<2;f++)
      #pragma unroll
      for(int kk=0;kk<2;kk++)
        kA[f][kk]=ld16(K+(kt*32+f*16+(lane&15))*64+kk*32+(lane>>4)*8);
    f32x4 st[2][4]={};
    #pragma unroll
    for(int kk=0;kk<2;kk++)
      #pragma unroll
      for(int f=0;f<2;f++)
        #pragma unroll
        for(int qb=0;qb<4;qb++)
          st[f][qb]=__builtin_amdgcn_mfma_f32_16x16x32_bf16(kA[f][kk],qf[qb][kk],st[f][qb],0,0,0);

    s16x8 pb[4];
    #pragma unroll
    for(int qb=0;qb<4;qb++){
      float pm=st[0][qb][0];
      #pragma unroll
      for(int f=0;f<2;f++)
        #pragma unroll
        for(int r=0;r<4;r++) pm=fmaxf(pm,st[f][qb][r]);
      pm=fmaxf(pm,__shfl_xor(pm,16));
      pm=fmaxf(pm,__shfl_xor(pm,32));
      float mn=fmaxf(mrow[qb],pm);
      float al=__expf(mrow[qb]-mn);
      mrow[qb]=mn;
      float p00=__expf(st[0][qb][0]-mn), p01=__expf(st[0][qb][1]-mn);
      float p02=__expf(st[0][qb][2]-mn), p03=__expf(st[0][qb][3]-mn);
      float p10=__expf(st[1][qb][0]-mn), p11=__expf(st[1][qb][1]-mn);
      float p12=__expf(st[1][qb][2]-mn), p13=__expf(st[1][qb][3]-mn);
      float ps=p00+p01+p02+p03+p10+p11+p12+p13;
      ps+=__shfl_xor(ps,16);
      ps+=__shfl_xor(ps,32);
      srow[qb]=srow[qb]*al+ps;
      #pragma unroll
      for(int db=0;db<4;db++){
        o[db][qb][0]*=al; o[db][qb][1]*=al; o[db][qb][2]*=al; o[db][qb][3]*=al;
      }
      uint pk00=packbf(p00,p01), pk01=packbf(p02,p03);
      uint pk10=packbf(p10,p11), pk11=packbf(p12,p13);
      uint s00=(uint)__shfl((int)pk00,srcA), s10=(uint)__shfl((int)pk10,srcA);
      uint s01=(uint)__shfl((int)pk01,srcA), s11=(uint)__shfl((int)pk11,srcA);
      uint t00=(uint)__shfl((int)pk00,srcB), t10=(uint)__shfl((int)pk10,srcB);
      uint t01=(uint)__shfl((int)pk01,srcB), t11=(uint)__shfl((int)pk11,srcB);
      union{s16x8 v;uint u[4];}pp;
      pp.u[0]=hi?s10:s00;
      pp.u[1]=hi?s11:s01;
      pp.u[2]=hi?t10:t00;
      pp.u[3]=hi?t11:t01;
      pb[qb]=pp.v;
    }
    s16x8 vA[4];
    #pragma unroll
    for(int db=0;db<4;db++)
      vA[db]=ld16(VT+(db*16+(lane&15))*256+kt*32+(lane>>4)*8);
    #pragma unroll
    for(int db=0;db<4;db++)
      #pragma unroll
      for(int qb=0;qb<4;qb++)
        o[db][qb]=__builtin_amdgcn_mfma_f32_16x16x32_bf16(vA[db],pb[qb],o[db][qb],0,0,0);
  }

  #pragma unroll
  for(int db=0;db<4;db++)
    #pragma unroll
    for(int qb=0;qb<4;qb++)
      #pragma unroll
      for(int r=0;r<4;r++){
        int d=db*16+(lane>>4)*4+r;
        int q=qb*16+(lane&15);
        ol[wave][q][d]=f2bf(o[db][qb][r]/srow[qb]);
      }
  __syncthreads();
  #pragma unroll
  for(int it=0;it<8;it++){
    int q=wave*64+it*8+(lane>>3);
    int cc=lane&7;
    s16x8 x=*(const s16x8*)&ol[wave][it*8+(lane>>3)][cc*8];
    *(s16x8*)&out[((long)(b*256+q)<<10)+h*64+cc*8]=x;
  }
}

// ---------------- host ------------------------------------------------------
extern "C" void kernel_launch(void* const* d_in, const int* in_sizes, int n_in,
                              void* d_out, int out_size, void* d_ws, size_t ws_size,
                              hipStream_t stream){
  const long M=16384;
  char* ws=(char*)d_ws;
  size_t off=0;
  auto alloc=[&](size_t b){ void* p=ws+off; off+=(b+255)&~(size_t)255; return p; };
  int*   flag =(int*)  alloc(256);
  float* cosT =(float*)alloc(256*64*4);
  float* sinT =(float*)alloc(256*64*4);
  float* biasF=(float*)alloc(1024*4);
  short* qbf  =(short*)alloc((size_t)M*1024*2);   // reused as attn_out
  short* kvbf =(short*)alloc((size_t)M*768*2);
  short* WqT  =(short*)alloc((size_t)1024*1024*2);
  short* WkvT =(short*)alloc((size_t)2048*768*2);
  short* WpT  =(short*)alloc((size_t)1024*1024*2);
  short* qhB  =(short*)alloc((size_t)16777216*2);
  short* kbuf =(short*)alloc((size_t)16777216*2);
  short* vtb  =(short*)alloc((size_t)16777216*2);

  k_detect<<<1,256,0,stream>>>((const uint*)d_in[0],flag);
  k_tables<<<64,256,0,stream>>>(cosT,sinT);
  k_bias<<<4,256,0,stream>>>(d_in[5],biasF,flag);
  k_convert<<<2048,256,0,stream>>>(d_in[0],qbf,(long)M*1024/8,flag);
  k_convert<<<2048,256,0,stream>>>(d_in[1],kvbf,(long)M*768/8,flag);
  k_transpose<<<512,256,0,stream>>>(d_in[2],WqT,1024,1024,flag);
  k_transpose<<<768,256,0,stream>>>(d_in[3],WkvT,768,2048,flag);
  k_transpose<<<512,256,0,stream>>>(d_in[4],WpT,1024,1024,flag);

  k_gemm8<0><<<256,512,0,stream>>>(qbf ,WqT ,1024,2,qhB ,nullptr,cosT,sinT,biasF,flag,nullptr);
  k_gemm8<1><<<512,512,0,stream>>>(kvbf,WkvT, 768,3,kbuf,vtb    ,cosT,sinT,biasF,flag,nullptr);
  k_attn<<<1024,256,0,stream>>>(qhB,kbuf,vtb,qbf);
  k_gemm8<2><<<256,512,0,stream>>>(qbf ,WpT ,1024,2,nullptr,nullptr,cosT,sinT,biasF,flag,d_out);
}

// Round 4
// 263.903 us; speedup vs baseline: 1.2922x; 1.0263x over previous
//
#include <hip/hip_runtime.h>
#include <hip/hip_bf16.h>
#include <math.h>

// CrossAttention fused pipeline, bf16 MFMA everywhere.
// B=64, N=256, C=1024, H=16, hd=64, sem=768, M=B*N=16384.
// R4: GEMM MFMA -> 32x32x16 (2495 vs 2176 TF rate, m119); EPI0+EPI1 merged
// into one 768-block dispatch; all prep fused into one grid-stride kernel.

typedef unsigned int uint;
typedef __attribute__((ext_vector_type(4)))  short s16x4;
typedef __attribute__((ext_vector_type(8)))  short s16x8;
typedef __attribute__((ext_vector_type(4)))  float f32x4;
typedef __attribute__((ext_vector_type(16))) float f32x16;

#define AS1 __attribute__((address_space(1)))
#define AS3 __attribute__((address_space(3)))

__device__ __forceinline__ short f2bf(float x){
  union{float f;uint u;}v; v.f=x;
  return (short)((v.u + 0x7FFFu + ((v.u>>16)&1u))>>16);   // RNE
}
__device__ __forceinline__ float bf2f(short s){
  union{float f;uint u;}v; v.u=((uint)(unsigned short)s)<<16; return v.f;
}
__device__ __forceinline__ uint packbf(float a,float b){
  return (uint)(unsigned short)f2bf(a) | ((uint)(unsigned short)f2bf(b)<<16);
}
__device__ __forceinline__ void gl_lds16(const void* g, void* l){
  __builtin_amdgcn_global_load_lds((const AS1 uint*)g, (AS3 uint*)l, 16, 0, 0);
}
__device__ __forceinline__ s16x8 ld16(const short* p){ return *(const s16x8*)p; }

// ---------------- dtype detection -------------------------------------------
__global__ void k_detect(const uint* q, int* flag){
  __shared__ int cnt;
  if(threadIdx.x==0) cnt=0;
  __syncthreads();
  int c=0;
  for(int i=threadIdx.x;i<4096;i+=256){
    uint e=(q[i]>>7)&0xFFu;
    if(e>=120u && e<=130u) c++;
  }
  atomicAdd(&cnt,c);
  __syncthreads();
  if(threadIdx.x==0) *flag = (cnt>2048)?0:1;
}

// ---------------- fused prep: tables + bias + 3 transposes + 2 converts -----
__global__ void k_prep(const void* Wq, const void* Wkv, const void* Wp,
                       const void* bsrc, const void* qsrc, const void* kvsrc,
                       short* WqT, short* WkvT, short* WpT, float* biasF,
                       float* cosT, float* sinT, short* qbf, short* kvbf,
                       const int* flag){
  const int f=*flag;
  const long S0=16384, S1=S0+1024, S2=S1+131072, S3=S2+196608, S4=S3+131072,
             S5=S4+2097152, S6=S5+1572864;
  const long stride=(long)gridDim.x*blockDim.x;
  for(long idx=(long)blockIdx.x*blockDim.x+threadIdx.x; idx<S6; idx+=stride){
    if(idx<S0){                       // RoPE tables (f64 to match numpy)
      int t=(int)idx, n=t>>6, d=t&63;
      int i=n>>4, j=n&15, p=(d&31)>>1;
      double fr=pow(10000.0, -(double)(2*p)/32.0);
      double tt=(d<32)?(double)i:(double)j;
      double a=tt*fr;
      cosT[t]=(float)cos(a); sinT[t]=(float)sin(a);
    } else if(idx<S1){                // bias -> f32
      int t=(int)(idx-S0);
      biasF[t]= f ? ((const float*)bsrc)[t] : bf2f(((const short*)bsrc)[t]);
    } else if(idx<S4){                // weight transposes (KxN -> NxK bf16)
      const void* W; short* WT; int K,Nn; long g;
      if(idx<S2){ W=Wq;  WT=WqT;  K=1024; Nn=1024; g=idx-S1; }
      else if(idx<S3){ W=Wkv; WT=WkvT; K=768; Nn=2048; g=idx-S2; }
      else { W=Wp;  WT=WpT;  K=1024; Nn=1024; g=idx-S3; }
      int n=(int)(g%Nn); int k0=(int)(g/Nn)*8;
      s16x8 o;
      #pragma unroll
      for(int j=0;j<8;j++){
        o[j]= f ? f2bf(((const float*)W)[(long)(k0+j)*Nn+n])
                : ((const short*)W)[(long)(k0+j)*Nn+n];
      }
      *(s16x8*)&WT[(long)n*K+k0]=o;
    } else {                          // activations -> bf16 (x8 groups)
      const void* src; short* dst; long i;
      if(idx<S5){ src=qsrc; dst=qbf; i=idx-S4; }
      else { src=kvsrc; dst=kvbf; i=idx-S5; }
      s16x8 o;
      if(f){
        const float4* s=(const float4*)src;
        float4 a=s[i*2], b=s[i*2+1];
        o[0]=f2bf(a.x);o[1]=f2bf(a.y);o[2]=f2bf(a.z);o[3]=f2bf(a.w);
        o[4]=f2bf(b.x);o[5]=f2bf(b.y);o[6]=f2bf(b.z);o[7]=f2bf(b.w);
      }else{
        o=((const s16x8*)src)[i];
      }
      ((s16x8*)dst)[i]=o;
    }
  }
}

// ---------------- 8-phase GEMM (32x32x16 MFMA), fused epilogues -------------
// Tile 256x256, BK=64, 512 threads = 8 waves (2Mx4N), wave owns 128x64 =
// 4x2 frags of 32x32. LDS 128KiB = 2dbuf x {A,B} x 2half x (128x64 bf16).
// Swizzle: 16B slot s of row r holds chunk s^((r>>1)&7) (involution, both
// sides). Per phase: {ds_read subtile || stage half-tile; BAR; lgkm0; 8 MFMA;
// BAR}. vmcnt(4) once per K-tile. MODE 0 = merged QKV (wg<256: q@Wq ->RoPE
// qh; else kv@Wkv -> RoPE k / transposed v). MODE 1 = proj (+bias -> d_out).
#define BAR   __builtin_amdgcn_s_barrier()
#define LGKM0 asm volatile("s_waitcnt lgkmcnt(0)" ::: "memory")
#define VMC4  asm volatile("s_waitcnt vmcnt(4)" ::: "memory")
#define PRIO1 __builtin_amdgcn_s_setprio(1)
#define PRIO0 __builtin_amdgcn_s_setprio(0)

#define MM(H,V,BR) do{ \
  _Pragma("unroll") for(int ks_=0;ks_<4;ks_++){ \
    _Pragma("unroll") for(int mf_=0;mf_<2;mf_++){ \
      acc[(H)*2+mf_][V]=__builtin_amdgcn_mfma_f32_32x32x16_bf16( \
        aR[mf_][ks_],BR[ks_],acc[(H)*2+mf_][V],0,0,0); \
  }} }while(0)

#define HALFIT(BUF,TA,TB) do{ \
  const short* RA=&lds[BUF][0][wm][0]; \
  const short* RB=&lds[BUF][1][0][0]; \
  ldA(RA,0,aR); ldB(RB,0,bR0); stage(0,0,TA); \
  BAR; LGKM0; PRIO1; MM(0,0,bR0); PRIO0; BAR; \
  ldB(RB,1,bR1); stage(0,1,TA); \
  BAR; LGKM0; PRIO1; MM(0,1,bR1); PRIO0; BAR; \
  ldA(RA,1,aR); stage(1,0,TB); \
  BAR; LGKM0; PRIO1; MM(1,1,bR1); PRIO0; BAR; \
  stage(1,1,TB); \
  BAR; PRIO1; MM(1,0,bR0); PRIO0; VMC4; BAR; \
}while(0)

template<int MODE>
__launch_bounds__(512,2)
__global__ void k_gemm8(const short* __restrict__ Aq, const short* __restrict__ Bq,
                        const short* __restrict__ Akv, const short* __restrict__ Bkv,
                        short* __restrict__ out0, short* __restrict__ out1,
                        short* __restrict__ out2,
                        const float* __restrict__ cosT, const float* __restrict__ sinT,
                        const float* __restrict__ bias, const int* __restrict__ flag,
                        void* __restrict__ dout){
  __shared__ __align__(16) short lds[2][2][2][8192];  // [dbuf][A/B][half][128*64]
  const int tid=threadIdx.x, lane=tid&63, wave=tid>>6;
  const int ln31=lane&31, l5=lane>>5;
  const int wm=wave>>2, wn=wave&3;
  // XCD-aware bijective block swizzle (nwg % 8 == 0)
  const int nwg=gridDim.x, cpx=nwg>>3;
  const int wg=((int)blockIdx.x&7)*cpx+((int)blockIdx.x>>3);
  int role, tm, tn, Kdim;
  const short *Ag, *Bg;
  if(MODE==1){
    role=2; tn=wg&3; tm=wg>>2; Kdim=1024;
    Ag=Aq+(long)tm*256*1024; Bg=Bq+(long)tn*256*1024;
  } else {
    if(wg<256){ role=0; tn=wg&3; tm=wg>>2; Kdim=1024;
      Ag=Aq+(long)tm*256*1024; Bg=Bq+(long)tn*256*1024; }
    else { role=1; int w=wg-256; tn=w&7; tm=w>>3; Kdim=768;
      Ag=Akv+(long)tm*256*768; Bg=Bkv+(long)tn*256*768; }
  }
  const int NT=Kdim>>6;
  const int fl=(MODE==1)? *flag : 0;
  f32x16 acc[4][2]={};
  s16x8 aR[2][4], bR0[4], bR1[4];

  auto stage=[&](int op,int hf,int kt){
    int ktw=(kt>=NT)?kt-NT:kt;               // tail wrap, memory-safe
    const short* G=(op? Bg:Ag)+((long)(hf*128))*Kdim+ktw*64;
    short* R=&lds[kt&1][op][hf][0];          // NT even -> parity preserved
    #pragma unroll
    for(int l=0;l<2;l++){
      int lr=l*64+wave*8+(lane>>3);
      int c=(lane&7)^((lr>>1)&7);            // pre-swizzled global source
      gl_lds16(G+(long)lr*Kdim+c*8, R+l*4096+wave*512+lane*8);
    }
  };
  auto ldA=[&](const short* R,int h,s16x8 (&a)[2][4]){
    #pragma unroll
    for(int mf=0;mf<2;mf++){
      int lr=h*64+mf*32+ln31;
      int sw=(lr>>1)&7;
      #pragma unroll
      for(int ks=0;ks<4;ks++){
        int slot=(ks*2+l5)^sw;
        a[mf][ks]=*(const s16x8*)&R[lr*64+slot*8];
      }
    }
  };
  auto ldB=[&](const short* R0,int v,s16x8 (&b)[4]){
    int row=wn*64+v*32+ln31;
    const short* R=R0+(row>>7)*8192;
    int lr=row&127;
    int sw=(lr>>1)&7;
    #pragma unroll
    for(int ks=0;ks<4;ks++){
      int slot=(ks*2+l5)^sw;
      b[ks]=*(const s16x8*)&R[lr*64+slot*8];
    }
  };

  // prologue: T0.B, T0.A, T1.B staged; wait all but last 4 -> T0 resident
  stage(1,0,0); stage(1,1,0); stage(0,0,0); stage(0,1,0);
  stage(1,0,1); stage(1,1,1);
  VMC4;
  BAR;

  for(int t=0;t<NT;t+=2){
    HALFIT(0, t+1, t+2);
    HALFIT(1, t+2, t+3);
  }

  // ---------------- epilogue (32x32 C/D: col=lane&31, row=(r&3)+8*(r>>2)+4*l5)
  const int mb=tm*256+wm*128, nb=tn*256+wn*64;
  #pragma unroll
  for(int mf=0;mf<4;mf++)
  #pragma unroll
  for(int nf=0;nf<2;nf++){
    const int n=nb+nf*32+ln31;
    if(MODE==1){
      float bi=bias[n];
      #pragma unroll
      for(int r=0;r<16;r++){
        int m=mb+mf*32+(r&3)+8*(r>>2)+4*l5;
        float o=acc[mf][nf][r]+bi;
        long idx=((long)m<<10)+n;
        if(fl) ((float*)dout)[idx]=o;
        else   ((short*)dout)[idx]=f2bf(o);
      }
    } else if(role==0){
      int h=n>>6, d=n&63;
      float c=cosT[0], s=0.f; // per-element below (nn varies per r)
      #pragma unroll
      for(int r=0;r<16;r++){
        int m=mb+mf*32+(r&3)+8*(r>>2)+4*l5;
        int b=m>>8, nn=m&255;
        float v=acc[mf][nf][r];
        float part=__shfl_xor(v,1);
        c=cosT[(nn<<6)+d]; s=sinT[(nn<<6)+d];
        float rot=(d&1)?part:-part;
        out0[(((long)(b*16+h)*256+nn)<<6)+d]=f2bf((v*c+rot*s)*0.125f);
      }
    } else {
      if(n<1024){   // uniform per block (tn<4): K-head with RoPE
        int h=(n>>6)&15, d=n&63;
        #pragma unroll
        for(int r=0;r<16;r++){
          int m=mb+mf*32+(r&3)+8*(r>>2)+4*l5;
          int b=m>>8, nn=m&255;
          float v=acc[mf][nf][r];
          float part=__shfl_xor(v,1);
          float c=cosT[(nn<<6)+d], s=sinT[(nn<<6)+d];
          float rot=(d&1)?part:-part;
          out1[(((long)(b*16+h)*256+nn)<<6)+d]=f2bf(v*c+rot*s);
        }
      }else{        // V, written pre-transposed (B,H,64,256)
        int h=(n>>6)&15, d=n&63;
        #pragma unroll
        for(int rq=0;rq<4;rq++){
          int m0=mb+mf*32+8*rq+4*l5;
          int b=m0>>8, nn0=m0&255;
          s16x4 pk;
          #pragma unroll
          for(int j=0;j<4;j++) pk[j]=f2bf(acc[mf][nf][rq*4+j]);
          *(s16x4*)&out2[(((long)(b*16+h)*64+d)<<8)+nn0]=pk;
        }
      }
    }
  }
}

// ---------------- attention: 1 block per (b,h), 4 waves x 64 q-rows ---------
// Swapped QK^T: ST = mfma(K,Q) => D[kv=(l>>4)*4+r][q=l&15]; softmax per q is
// lane-local + 2 shfl_xor. P^T redistributed in-register to the PV B-operand.
// PV: O^T = mfma(VT, P^T) => D[d=(l>>4)*4+r][q=l&15]. LDS-transposed epilogue.
__launch_bounds__(256,2)
__global__ void k_attn(const short* qh, const short* kb, const short* vt, short* out){
  __shared__ __align__(16) short ol[4][64][72];
  int bh=blockIdx.x, b=bh>>4, h=bh&15;
  int tid=threadIdx.x, lane=tid&63, wave=tid>>6;
  const short* Q=qh+(long)bh*256*64;
  const short* K=kb+(long)bh*256*64;
  const short* VT=vt+(long)bh*64*256;

  s16x8 qf[4][2];
  #pragma unroll
  for(int qb=0;qb<4;qb++)
    #pragma unroll
    for(int kk=0;kk<2;kk++)
      qf[qb][kk]=ld16(Q+(wave*64+qb*16+(lane&15))*64+kk*32+(lane>>4)*8);

  f32x4 o[4][4]={};
  float mrow[4]={-INFINITY,-INFINITY,-INFINITY,-INFINITY};
  float srow[4]={0.f,0.f,0.f,0.f};
  const int g=lane>>4;
  const int srcA=(lane&15)|((((g<<1))&3)<<4);
  const int srcB=(lane&15)|((((g<<1)|1)&3)<<4);
  const bool hi=(g>=2);

  for(int kt=0;kt<8;kt++){
    s16x8 kA[2][2];
    #pragma unroll
    for(int f=0;f<2;f++)
      #pragma unroll
      for(int kk=0;kk<2;kk++)
        kA[f][kk]=ld16(K+(kt*32+f*16+(lane&15))*64+kk*32+(lane>>4)*8);
    f32x4 st[2][4]={};
    #pragma unroll
    for(int kk=0;kk<2;kk++)
      #pragma unroll
      for(int f=0;f<2;f++)
        #pragma unroll
        for(int qb=0;qb<4;qb++)
          st[f][qb]=__builtin_amdgcn_mfma_f32_16x16x32_bf16(kA[f][kk],qf[qb][kk],st[f][qb],0,0,0);

    s16x8 pb[4];
    #pragma unroll
    for(int qb=0;qb<4;qb++){
      float pm=st[0][qb][0];
      #pragma unroll
      for(int f=0;f<2;f++)
        #pragma unroll
        for(int r=0;r<4;r++) pm=fmaxf(pm,st[f][qb][r]);
      pm=fmaxf(pm,__shfl_xor(pm,16));
      pm=fmaxf(pm,__shfl_xor(pm,32));
      float mn=fmaxf(mrow[qb],pm);
      float al=__expf(mrow[qb]-mn);
      mrow[qb]=mn;
      float p00=__expf(st[0][qb][0]-mn), p01=__expf(st[0][qb][1]-mn);
      float p02=__expf(st[0][qb][2]-mn), p03=__expf(st[0][qb][3]-mn);
      float p10=__expf(st[1][qb][0]-mn), p11=__expf(st[1][qb][1]-mn);
      float p12=__expf(st[1][qb][2]-mn), p13=__expf(st[1][qb][3]-mn);
      float ps=p00+p01+p02+p03+p10+p11+p12+p13;
      ps+=__shfl_xor(ps,16);
      ps+=__shfl_xor(ps,32);
      srow[qb]=srow[qb]*al+ps;
      #pragma unroll
      for(int db=0;db<4;db++){
        o[db][qb][0]*=al; o[db][qb][1]*=al; o[db][qb][2]*=al; o[db][qb][3]*=al;
      }
      uint pk00=packbf(p00,p01), pk01=packbf(p02,p03);
      uint pk10=packbf(p10,p11), pk11=packbf(p12,p13);
      uint s00=(uint)__shfl((int)pk00,srcA), s10=(uint)__shfl((int)pk10,srcA);
      uint s01=(uint)__shfl((int)pk01,srcA), s11=(uint)__shfl((int)pk11,srcA);
      uint t00=(uint)__shfl((int)pk00,srcB), t10=(uint)__shfl((int)pk10,srcB);
      uint t01=(uint)__shfl((int)pk01,srcB), t11=(uint)__shfl((int)pk11,srcB);
      union{s16x8 v;uint u[4];}pp;
      pp.u[0]=hi?s10:s00;
      pp.u[1]=hi?s11:s01;
      pp.u[2]=hi?t10:t00;
      pp.u[3]=hi?t11:t01;
      pb[qb]=pp.v;
    }
    s16x8 vA[4];
    #pragma unroll
    for(int db=0;db<4;db++)
      vA[db]=ld16(VT+(db*16+(lane&15))*256+kt*32+(lane>>4)*8);
    #pragma unroll
    for(int db=0;db<4;db++)
      #pragma unroll
      for(int qb=0;qb<4;qb++)
        o[db][qb]=__builtin_amdgcn_mfma_f32_16x16x32_bf16(vA[db],pb[qb],o[db][qb],0,0,0);
  }

  #pragma unroll
  for(int db=0;db<4;db++)
    #pragma unroll
    for(int qb=0;qb<4;qb++)
      #pragma unroll
      for(int r=0;r<4;r++){
        int d=db*16+(lane>>4)*4+r;
        int q=qb*16+(lane&15);
        ol[wave][q][d]=f2bf(o[db][qb][r]/srow[qb]);
      }
  __syncthreads();
  #pragma unroll
  for(int it=0;it<8;it++){
    int q=wave*64+it*8+(lane>>3);
    int cc=lane&7;
    s16x8 x=*(const s16x8*)&ol[wave][it*8+(lane>>3)][cc*8];
    *(s16x8*)&out[((long)(b*256+q)<<10)+h*64+cc*8]=x;
  }
}

// ---------------- host ------------------------------------------------------
extern "C" void kernel_launch(void* const* d_in, const int* in_sizes, int n_in,
                              void* d_out, int out_size, void* d_ws, size_t ws_size,
                              hipStream_t stream){
  const long M=16384;
  char* ws=(char*)d_ws;
  size_t off=0;
  auto alloc=[&](size_t b){ void* p=ws+off; off+=(b+255)&~(size_t)255; return p; };
  int*   flag =(int*)  alloc(256);
  float* cosT =(float*)alloc(256*64*4);
  float* sinT =(float*)alloc(256*64*4);
  float* biasF=(float*)alloc(1024*4);
  short* qbf  =(short*)alloc((size_t)M*1024*2);   // reused as attn_out
  short* kvbf =(short*)alloc((size_t)M*768*2);
  short* WqT  =(short*)alloc((size_t)1024*1024*2);
  short* WkvT =(short*)alloc((size_t)2048*768*2);
  short* WpT  =(short*)alloc((size_t)1024*1024*2);
  short* qhB  =(short*)alloc((size_t)16777216*2);
  short* kbuf =(short*)alloc((size_t)16777216*2);
  short* vtb  =(short*)alloc((size_t)16777216*2);

  k_detect<<<1,256,0,stream>>>((const uint*)d_in[0],flag);
  k_prep<<<2048,256,0,stream>>>(d_in[2],d_in[3],d_in[4],d_in[5],d_in[0],d_in[1],
                                WqT,WkvT,WpT,biasF,cosT,sinT,qbf,kvbf,flag);
  k_gemm8<0><<<768,512,0,stream>>>(qbf,WqT,kvbf,WkvT,qhB,kbuf,vtb,
                                   cosT,sinT,biasF,flag,nullptr);
  k_attn<<<1024,256,0,stream>>>(qhB,kbuf,vtb,qbf);
  k_gemm8<1><<<256,512,0,stream>>>(qbf,WpT,nullptr,nullptr,nullptr,nullptr,nullptr,
                                   cosT,sinT,biasF,flag,d_out);
}